// Round 13
// baseline (1633.621 us; speedup 1.0000x reference)
//
#include <hip/hip_runtime.h>
#include <hip/hip_bf16.h>
#include <math.h>

typedef __hip_bfloat16 bf16;
__device__ __forceinline__ float b2f(bf16 x) { return __bfloat162float(x); }
// order-preserving float->uint key (larger float => larger key)
__device__ __forceinline__ unsigned fkey(float f) {
    unsigned u = __float_as_uint(f);
    return (u & 0x80000000u) ? ~u : (u | 0x80000000u);
}

#define LN_EPS 1e-12f
#define NEG_INF (-3.0e38f)

__global__ __launch_bounds__(256)
void copy_int_kernel(const int* __restrict__ src, int* __restrict__ dst, int n)
{
    int i = blockIdx.x * 256 + threadIdx.x;
    if (i < n) dst[i] = src[i];
}

// ============================ LayerNorm (f32 -> f32, f64 stats) ============================
__global__ __launch_bounds__(256)
void ln_kernel(const float* __restrict__ in, const float* __restrict__ g,
               const float* __restrict__ b, float* __restrict__ out)
{
    const int D = 1024;
    int row = blockIdx.x, tid = threadIdx.x;
    size_t base = (size_t)row * D + tid * 4;
    float x[4];
    #pragma unroll
    for (int i = 0; i < 4; ++i) x[i] = in[base + i];
    double s  = (double)x[0] + x[1] + x[2] + x[3];
    double sq = (double)x[0]*x[0] + (double)x[1]*x[1] + (double)x[2]*x[2] + (double)x[3]*x[3];
    __shared__ double rs[256], rq[256];
    rs[tid] = s; rq[tid] = sq;
    __syncthreads();
    for (int o = 128; o > 0; o >>= 1) {
        if (tid < o) { rs[tid] += rs[tid + o]; rq[tid] += rq[tid + o]; }
        __syncthreads();
    }
    double mean = rs[0] * (1.0 / D);
    double var  = rq[0] * (1.0 / D) - mean * mean;
    double inv  = rsqrt(var + (double)LN_EPS);
    #pragma unroll
    for (int i = 0; i < 4; ++i) {
        int col = tid * 4 + i;
        out[base + i] = (float)(((double)x[i] - mean) * inv * (double)g[col] + (double)b[col]);
    }
}

// ============ generic NT GEMM 64x64 (kept ONLY for the f64 hash projections) ============
#define BM 64
#define BN 64
#define BK 16
template<typename ACC>
__global__ __launch_bounds__(256)
void gemm_nt_t(const float* __restrict__ A, int lda,
               const float* __restrict__ B, int ldb,
               const int* __restrict__ gatherB,
               const float* __restrict__ bias,
               const float* __restrict__ residual,
               void* __restrict__ out_, int oBf, int ldc, int mode,
               int M, int N, int Kd)
{
    __shared__ __align__(16) float As[BK][BM + 4];
    __shared__ __align__(16) float Bs[BK][BN + 4];
    int tid = threadIdx.x;
    int bm = blockIdx.y * BM, bn = blockIdx.x * BN;
    int lm  = tid >> 2;
    int lk4 = (tid & 3) * 4;
    int tm = (tid >> 4) * 4, tn = (tid & 15) * 4;
    ACC acc[4][4] = {};
    for (int k0 = 0; k0 < Kd; k0 += BK) {
        {
            const float* p = A + (size_t)(bm + lm) * lda + k0 + lk4;
            #pragma unroll
            for (int i = 0; i < 4; ++i) As[lk4 + i][lm] = p[i];
        }
        {
            int r = bn + lm;
            if (gatherB) r = gatherB[r] & 4095;
            const float* p = B + (size_t)r * ldb + k0 + lk4;
            #pragma unroll
            for (int i = 0; i < 4; ++i) Bs[lk4 + i][lm] = p[i];
        }
        __syncthreads();
        #pragma unroll
        for (int k = 0; k < BK; ++k) {
            float4 av = *(const float4*)&As[k][tm];
            float4 bw = *(const float4*)&Bs[k][tn];
            float avx[4] = {av.x, av.y, av.z, av.w};
            float bwx[4] = {bw.x, bw.y, bw.z, bw.w};
            #pragma unroll
            for (int i = 0; i < 4; ++i)
                #pragma unroll
                for (int j = 0; j < 4; ++j)
                    acc[i][j] += (ACC)avx[i] * (ACC)bwx[j];
        }
        __syncthreads();
    }
    #pragma unroll
    for (int i = 0; i < 4; ++i) {
        int m = bm + tm + i;
        #pragma unroll
        for (int j = 0; j < 4; ++j) {
            int n = bn + tn + j;
            ACC v = acc[i][j];
            if (bias) { int bi2 = gatherB ? (gatherB[n] & 4095) : n; v += (ACC)bias[bi2]; }
            if (residual) v += (ACC)residual[(size_t)m * ldc + n];
            size_t idx;
            if (mode == 0)      idx = (size_t)m * ldc + n;
            else if (mode == 1) idx = (size_t)(n >> 6) * ((size_t)M * 64) + (size_t)m * 64 + (n & 63);
            else                idx = (size_t)(n >> 3) * ((size_t)M * 8) + (size_t)m * 8 + (n & 7);
            if (oBf) ((bf16*)out_)[idx] = __float2bfloat16((float)v);
            else     ((float*)out_)[idx] = (float)v;
        }
    }
}

// ============ 128x64-tile f32 NT GEMM (8x4 acc/thread) — qkv/oproj/logits ============
// mode 0: out[m*ldc+n]   mode 1: head-blocked out
__global__ __launch_bounds__(256)
void gemm_f32_big(const float* __restrict__ A, int lda,
                  const float* __restrict__ B, int ldb,
                  const int* __restrict__ gatherB,
                  const float* __restrict__ bias,
                  const float* __restrict__ residual,
                  void* __restrict__ out_, int oBf, int ldc, int mode,
                  int M, int Kd,
                  size_t aStride, size_t oStride, int gStride)
{
    __shared__ __align__(16) float As[16][132];
    __shared__ __align__(16) float Bs[16][68];
    int tid = threadIdx.x;
    const float* Ab = A + (size_t)blockIdx.z * aStride;
    const int* gb = gatherB ? gatherB + blockIdx.z * gStride : nullptr;
    size_t oOff = (size_t)blockIdx.z * oStride;
    int bm = blockIdx.y * 128, bn = blockIdx.x * 64;
    int lmA = tid >> 1, kA = (tid & 1) * 8;
    int lmB = tid >> 2, kB = (tid & 3) * 4;
    int rB = bn + lmB; if (gb) rB = gb[rB] & 4095;
    int tm = (tid >> 4) * 8, tn = (tid & 15) * 4;
    float acc[8][4] = {};
    for (int k0 = 0; k0 < Kd; k0 += 16) {
        {
            const float* pa = Ab + (size_t)(bm + lmA) * lda + k0 + kA;
            float4 a0 = *(const float4*)pa;
            float4 a1 = *(const float4*)(pa + 4);
            As[kA+0][lmA]=a0.x; As[kA+1][lmA]=a0.y; As[kA+2][lmA]=a0.z; As[kA+3][lmA]=a0.w;
            As[kA+4][lmA]=a1.x; As[kA+5][lmA]=a1.y; As[kA+6][lmA]=a1.z; As[kA+7][lmA]=a1.w;
        }
        {
            const float* pb = B + (size_t)rB * ldb + k0 + kB;
            float4 b0 = *(const float4*)pb;
            Bs[kB+0][lmB]=b0.x; Bs[kB+1][lmB]=b0.y; Bs[kB+2][lmB]=b0.z; Bs[kB+3][lmB]=b0.w;
        }
        __syncthreads();
        #pragma unroll
        for (int k = 0; k < 16; ++k) {
            float4 alo = *(const float4*)&As[k][tm];
            float4 ahi = *(const float4*)&As[k][tm + 4];
            float4 bw  = *(const float4*)&Bs[k][tn];
            float avx[8] = {alo.x, alo.y, alo.z, alo.w, ahi.x, ahi.y, ahi.z, ahi.w};
            float bwx[4] = {bw.x, bw.y, bw.z, bw.w};
            #pragma unroll
            for (int i = 0; i < 8; ++i)
                #pragma unroll
                for (int j = 0; j < 4; ++j)
                    acc[i][j] += avx[i] * bwx[j];
        }
        __syncthreads();
    }
    #pragma unroll
    for (int i = 0; i < 8; ++i) {
        int m = bm + tm + i;
        #pragma unroll
        for (int j = 0; j < 4; ++j) {
            int n = bn + tn + j;
            float v = acc[i][j];
            if (bias) { int bi2 = gb ? (gb[n] & 4095) : n; v += bias[bi2]; }
            if (residual) v += residual[(size_t)m * ldc + n];
            size_t idx;
            if (mode == 0) idx = (size_t)m * ldc + n;
            else           idx = (size_t)(n >> 6) * ((size_t)M * 64) + (size_t)m * 64 + (n & 63);
            if (oBf) ((bf16*)out_)[oOff + idx] = __float2bfloat16(v);
            else     ((float*)out_)[oOff + idx] = v;
        }
    }
}

// ============ QKV fused (z selects Q/K/V), 128x64 tiles, f32, head-blocked out ============
__global__ __launch_bounds__(256)
void qkv_kernel(const float* __restrict__ A,
                const float* __restrict__ Wq, const float* __restrict__ Wk, const float* __restrict__ Wv,
                const float* __restrict__ bq, const float* __restrict__ bk, const float* __restrict__ bv,
                float* __restrict__ qo, float* __restrict__ ko, float* __restrict__ vo)
{
    const int lda = 1024, ldb = 1024, Kd = 1024, M = 2048;
    const float* B    = (blockIdx.z == 0) ? Wq : (blockIdx.z == 1) ? Wk : Wv;
    const float* bias = (blockIdx.z == 0) ? bq : (blockIdx.z == 1) ? bk : bv;
    float* out        = (blockIdx.z == 0) ? qo : (blockIdx.z == 1) ? ko : vo;
    __shared__ __align__(16) float As[16][132];
    __shared__ __align__(16) float Bs[16][68];
    int tid = threadIdx.x;
    int bm = blockIdx.y * 128, bn = blockIdx.x * 64;
    int lmA = tid >> 1, kA = (tid & 1) * 8;
    int lmB = tid >> 2, kB = (tid & 3) * 4;
    int tm = (tid >> 4) * 8, tn = (tid & 15) * 4;
    float acc[8][4] = {};
    for (int k0 = 0; k0 < Kd; k0 += 16) {
        {
            const float* pa = A + (size_t)(bm + lmA) * lda + k0 + kA;
            float4 a0 = *(const float4*)pa;
            float4 a1 = *(const float4*)(pa + 4);
            As[kA+0][lmA]=a0.x; As[kA+1][lmA]=a0.y; As[kA+2][lmA]=a0.z; As[kA+3][lmA]=a0.w;
            As[kA+4][lmA]=a1.x; As[kA+5][lmA]=a1.y; As[kA+6][lmA]=a1.z; As[kA+7][lmA]=a1.w;
        }
        {
            const float* pb = B + (size_t)(bn + lmB) * ldb + k0 + kB;
            float4 b0 = *(const float4*)pb;
            Bs[kB+0][lmB]=b0.x; Bs[kB+1][lmB]=b0.y; Bs[kB+2][lmB]=b0.z; Bs[kB+3][lmB]=b0.w;
        }
        __syncthreads();
        #pragma unroll
        for (int k = 0; k < 16; ++k) {
            float4 alo = *(const float4*)&As[k][tm];
            float4 ahi = *(const float4*)&As[k][tm + 4];
            float4 bw  = *(const float4*)&Bs[k][tn];
            float avx[8] = {alo.x, alo.y, alo.z, alo.w, ahi.x, ahi.y, ahi.z, ahi.w};
            float bwx[4] = {bw.x, bw.y, bw.z, bw.w};
            #pragma unroll
            for (int i = 0; i < 8; ++i)
                #pragma unroll
                for (int j = 0; j < 4; ++j)
                    acc[i][j] += avx[i] * bwx[j];
        }
        __syncthreads();
    }
    #pragma unroll
    for (int i = 0; i < 8; ++i) {
        int m = bm + tm + i;
        #pragma unroll
        for (int j = 0; j < 4; ++j) {
            int n = bn + tn + j;
            float v = acc[i][j] + bias[n];
            size_t idx = (size_t)(n >> 6) * ((size_t)M * 64) + (size_t)m * 64 + (n & 63);
            out[idx] = v;
        }
    }
}

// ==== output GEMM (z = chunk), 128x64 tiles: gelu(logits) @ W2[sids] + b2 + attnO -> d_out ====
__global__ __launch_bounds__(256)
void out_kernel(const bf16* __restrict__ logits, const float* __restrict__ W2,
                const int* __restrict__ sids, const float* __restrict__ b2w,
                const float* __restrict__ attnO, float* __restrict__ out)
{
    const int lda = 1024, ldb = 1024, ldc = 1024, Kd = 1024;
    size_t chOff = (size_t)blockIdx.z * 1048576;
    const bf16* A = logits + chOff;
    const int* gk = sids + blockIdx.z * 1024;
    const float* residual = attnO + chOff;
    __shared__ __align__(16) float As[16][132];
    __shared__ __align__(16) float Bs[16][68];
    int tid = threadIdx.x;
    int bm = blockIdx.y * 128, bn = blockIdx.x * 64;
    int lmA = tid >> 1, kA = (tid & 1) * 8;
    int kRow = tid >> 4, nOff = (tid & 15) * 4;
    int tm = (tid >> 4) * 8, tn = (tid & 15) * 4;
    float acc[8][4] = {};
    for (int k0 = 0; k0 < Kd; k0 += 16) {
        {
            const unsigned short* pa = (const unsigned short*)A + (size_t)(bm + lmA) * lda + k0 + kA;
            ushort4 u0 = *(const ushort4*)pa;
            ushort4 u1 = *(const ushort4*)(pa + 4);
            unsigned short us[8] = {u0.x, u0.y, u0.z, u0.w, u1.x, u1.y, u1.z, u1.w};
            #pragma unroll
            for (int i = 0; i < 8; ++i) {
                union { unsigned u; float f; } w; w.u = ((unsigned)us[i]) << 16;
                float x = w.f;
                As[kA + i][lmA] = 0.5f * x * (1.0f + erff(x * 0.70710678118654752f));
            }
        }
        {
            int r = gk[k0 + kRow] & 4095;
            float4 b0 = *(const float4*)(W2 + (size_t)r * ldb + bn + nOff);
            *(float4*)&Bs[kRow][nOff] = b0;
        }
        __syncthreads();
        #pragma unroll
        for (int k = 0; k < 16; ++k) {
            float4 alo = *(const float4*)&As[k][tm];
            float4 ahi = *(const float4*)&As[k][tm + 4];
            float4 bw  = *(const float4*)&Bs[k][tn];
            float avx[8] = {alo.x, alo.y, alo.z, alo.w, ahi.x, ahi.y, ahi.z, ahi.w};
            float bwx[4] = {bw.x, bw.y, bw.z, bw.w};
            #pragma unroll
            for (int i = 0; i < 8; ++i)
                #pragma unroll
                for (int j = 0; j < 4; ++j)
                    acc[i][j] += avx[i] * bwx[j];
        }
        __syncthreads();
    }
    #pragma unroll
    for (int i = 0; i < 8; ++i) {
        int m = bm + tm + i;
        #pragma unroll
        for (int j = 0; j < 4; ++j) {
            int n = bn + tn + j;
            float v = acc[i][j] + b2w[n] + residual[(size_t)m * ldc + n];
            out[chOff + (size_t)m * ldc + n] = v;
        }
    }
}

// ============================ flash attention v5 ============================
// Q-tile 64, thread owns rows {ty, ty+16, ty+32, ty+48} (conflict-free with stride 76)
// and cols tx+16j. All f32, no max-shift. Per-row FP order identical to v4.
__global__ __launch_bounds__(256)
void flash_kernel(const float* __restrict__ q, const float* __restrict__ k,
                  const float* __restrict__ v, const float* __restrict__ amask,
                  float* __restrict__ ctx, int hbase)
{
    int qt = blockIdx.x, hl = blockIdx.y, tid = threadIdx.x;
    int ty = tid >> 4, tx = tid & 15;
    __shared__ __align__(16) float Qs[64][76];
    __shared__ __align__(16) float KVs[64][76];
    __shared__ __align__(16) float St[64][76];
    __shared__ float lrow[64], msk[64];
    const float* qh = q + (size_t)hl * 131072 + (size_t)qt * 4096;
    #pragma unroll
    for (int rep = 0; rep < 4; ++rep) {
        int lin = rep * 1024 + tid * 4;
        int r = lin >> 6, c = lin & 63;
        float4 u = *(const float4*)(qh + r * 64 + c);
        Qs[r][c] = u.x; Qs[r][c+1] = u.y; Qs[r][c+2] = u.z; Qs[r][c+3] = u.w;
    }
    if (tid < 64) lrow[tid] = 0.0f;
    float o[4][4] = {};          // [row i][dim j], rows ty+16i, dims tx*4+j
    for (int kt = 0; kt < 32; ++kt) {
        const float* kh = k + (size_t)hl * 131072 + (size_t)kt * 4096;
        const float* vh = v + (size_t)hl * 131072 + (size_t)kt * 4096;
        #pragma unroll
        for (int rep = 0; rep < 4; ++rep) {
            int lin = rep * 1024 + tid * 4;
            int r = lin >> 6, c = lin & 63;
            float4 u = *(const float4*)(kh + r * 64 + c);
            KVs[r][c] = u.x; KVs[r][c+1] = u.y; KVs[r][c+2] = u.z; KVs[r][c+3] = u.w;
        }
        if (tid < 64) msk[tid] = 1000.0f * (1.0f - amask[kt * 64 + tid]);
        __syncthreads();
        // scores: 4 rows x 4 cols per lane
        float sc[4][4] = {};
        #pragma unroll 4
        for (int d = 0; d < 64; d += 4) {
            float4 qv[4];
            #pragma unroll
            for (int i = 0; i < 4; ++i) qv[i] = *(const float4*)&Qs[ty + 16 * i][d];
            #pragma unroll
            for (int j = 0; j < 4; ++j) {
                float4 kv = *(const float4*)&KVs[tx + 16 * j][d];
                #pragma unroll
                for (int i = 0; i < 4; ++i)
                    sc[i][j] += qv[i].x * kv.x + qv[i].y * kv.y + qv[i].z * kv.z + qv[i].w * kv.w;
            }
        }
        __syncthreads();   // K reads done -> KVs free for V
        float sum[4] = {};
        #pragma unroll
        for (int i = 0; i < 4; ++i) {
            #pragma unroll
            for (int j = 0; j < 4; ++j) {
                float p = expf(sc[i][j] * 0.125f - msk[tx + 16 * j]);
                St[ty + 16 * i][tx + 16 * j] = p;
                sum[i] += p;
            }
        }
        #pragma unroll
        for (int off = 1; off < 16; off <<= 1) {
            #pragma unroll
            for (int i = 0; i < 4; ++i) sum[i] += __shfl_xor(sum[i], off, 16);
        }
        if (tx == 0) {
            #pragma unroll
            for (int i = 0; i < 4; ++i) lrow[ty + 16 * i] += sum[i];
        }
        #pragma unroll
        for (int rep = 0; rep < 4; ++rep) {
            int lin = rep * 1024 + tid * 4;
            int r = lin >> 6, c = lin & 63;
            float4 w = *(const float4*)(vh + r * 64 + c);
            KVs[r][c] = w.x; KVs[r][c+1] = w.y; KVs[r][c+2] = w.z; KVs[r][c+3] = w.w;
        }
        __syncthreads();   // V + St ready
        for (int j2 = 0; j2 < 64; j2 += 4) {
            float4 pv[4];
            #pragma unroll
            for (int i = 0; i < 4; ++i) pv[i] = *(const float4*)&St[ty + 16 * i][j2];
            float pa[4][4];
            #pragma unroll
            for (int i = 0; i < 4; ++i) { pa[i][0]=pv[i].x; pa[i][1]=pv[i].y; pa[i][2]=pv[i].z; pa[i][3]=pv[i].w; }
            #pragma unroll
            for (int e = 0; e < 4; ++e) {
                float4 vv = *(const float4*)&KVs[j2 + e][tx * 4];
                #pragma unroll
                for (int i = 0; i < 4; ++i) {
                    o[i][0] += pa[i][e] * vv.x; o[i][1] += pa[i][e] * vv.y;
                    o[i][2] += pa[i][e] * vv.z; o[i][3] += pa[i][e] * vv.w;
                }
            }
        }
        __syncthreads();   // protect KVs/St for next kt
    }
    #pragma unroll
    for (int i = 0; i < 4; ++i) {
        int row = ty + 16 * i;
        float inv = 1.0f / lrow[row];
        size_t base = (size_t)(qt * 64 + row) * 1024 + (hbase + hl) * 64 + tx * 4;
        #pragma unroll
        for (int j = 0; j < 4; ++j) ctx[base + j] = o[i][j] * inv;
    }
}

// ============================ hashing / routing ============================
__global__ __launch_bounds__(256)
void code_n_kernel(const float* __restrict__ projn, int* __restrict__ code_n,
                   int* __restrict__ zero_base)
{
    int i = blockIdx.x * 256 + threadIdx.x;
    const float* p = projn + (size_t)i * 8;
    int code = 0;
    #pragma unroll
    for (int k = 0; k < 8; ++k) code |= ((int)(p[k] > 0.0f)) << k;
    code_n[i] = code;
    if (i < 49156) zero_base[i] = 0;
}

__global__ __launch_bounds__(256)
void code_t_kernel(float* __restrict__ pt, int* __restrict__ code_t)
{
    int i = blockIdx.x * 256 + threadIdx.x;
    int t = i >> 4, l = i & 15;
    float* p = pt + (size_t)t * 128 + l * 8;
    int code = 0;
    #pragma unroll
    for (int k = 0; k < 8; ++k) {
        float v = p[k];
        code |= ((int)(v > 0.0f)) << k;
        p[k] = tanhf(v);
    }
    code_t[l * 2048 + t] = code;
}

__global__ __launch_bounds__(256)
void hist_kernel(const int* __restrict__ code_t, int* __restrict__ hist)
{
    int i = blockIdx.x * 256 + threadIdx.x;
    int c = i >> 14, l = (i >> 10) & 15, t = i & 1023;
    int code = code_t[l * 2048 + c * 1024 + t] & 255;
    atomicAdd(&hist[(c * 16 + l) * 256 + code], 1);
}

__global__ __launch_bounds__(256)
void score_kernel(const int* __restrict__ hist, const int* __restrict__ code_n,
                  int* __restrict__ score, int* __restrict__ shist)
{
    int i = blockIdx.x * 256 + threadIdx.x;
    int c = i >> 12, n = i & 4095;
    int s = 0;
    #pragma unroll
    for (int l = 0; l < 16; ++l) s += hist[(c * 16 + l) * 256 + (code_n[l * 4096 + n] & 255)];
    if (s < 0) s = 0; if (s > 16384) s = 16384;
    score[c * 4096 + n] = s;
    atomicAdd(&shist[c * 16385 + s], 1);
}

__global__ __launch_bounds__(256)
void select_kernel(const int* __restrict__ shist, int* __restrict__ selmeta)
{
    int c = blockIdx.x, tid = threadIdx.x;
    const int* bins = shist + c * 16385;
    __shared__ int psum[256];
    int s = 0;
    for (int i = 0; i < 64; ++i) s += bins[tid * 64 + i];
    if (tid == 255) s += bins[16384];
    psum[tid] = s;
    __syncthreads();
    if (tid == 0) {
        int cum = 0, sstar = 0, cntge = 0;
        for (int t = 255; t >= 0; --t) {
            if (cum + psum[t] >= 1024) {
                int hi = (t == 255) ? 16384 : t * 64 + 63;
                for (int b = hi; b >= t * 64; --b) {
                    cum += bins[b];
                    if (cum >= 1024) { sstar = b; cntge = cum; break; }
                }
                break;
            }
            cum += psum[t];
        }
        selmeta[c * 2]     = sstar;
        selmeta[c * 2 + 1] = 1024 - (cntge - bins[sstar]);
    }
}

__global__ __launch_bounds__(256)
void build_sids_kernel(const int* __restrict__ score, const int* __restrict__ selmeta,
                       int* __restrict__ sids)
{
    int c = blockIdx.x, tid = threadIdx.x;
    const int* sc2 = score + c * 4096;
    int sstar = selmeta[c * 2], need_eq = selmeta[c * 2 + 1];
    __shared__ int scan[256];
    int base = tid * 16;
    int mysc[16];
    int eqc = 0;
    #pragma unroll
    for (int i = 0; i < 16; ++i) { mysc[i] = sc2[base + i]; eqc += (mysc[i] == sstar); }
    scan[tid] = eqc; __syncthreads();
    for (int o = 1; o < 256; o <<= 1) {
        int v = (tid >= o) ? scan[tid - o] : 0;
        __syncthreads();
        scan[tid] += v;
        __syncthreads();
    }
    int eqr = scan[tid] - eqc;
    __syncthreads();
    int selc = 0; unsigned flags = 0;
    #pragma unroll
    for (int i = 0; i < 16; ++i) {
        bool sel = false;
        if (mysc[i] > sstar) sel = true;
        else if (mysc[i] == sstar) { sel = (eqr < need_eq); eqr++; }
        if (sel) { flags |= (1u << i); selc++; }
    }
    scan[tid] = selc; __syncthreads();
    for (int o = 1; o < 256; o <<= 1) {
        int v = (tid >= o) ? scan[tid - o] : 0;
        __syncthreads();
        scan[tid] += v;
        __syncthreads();
    }
    int pos = scan[tid] - selc;
    #pragma unroll
    for (int i = 0; i < 16; ++i)
        if (flags & (1u << i)) { if (pos < 1024) sids[c * 1024 + pos] = base + i; pos++; }
}

__global__ __launch_bounds__(256)
void tanhpn_kernel(const float* __restrict__ projn, const int* __restrict__ sids,
                   float* __restrict__ tanhpn)
{
    int i = blockIdx.x * 256 + threadIdx.x;
    int c = i >> 17;
    int r = i & 131071;
    int s = r >> 7, j = r & 127;
    int l = j >> 3, k = j & 7;
    int n = sids[c * 1024 + s] & 4095;
    tanhpn[(size_t)c * 131072 + (size_t)s * 128 + j] = tanhf(projn[(size_t)l * 32768 + (size_t)n * 8 + k]);
}

// ============================ topk: radix-select per row ============================
__global__ __launch_bounds__(256)
void topk_kernel(const bf16* __restrict__ logits, const float* __restrict__ tanhpt,
                 const float* __restrict__ tanhpn, float* __restrict__ trip)
{
    int t = blockIdx.x;
    int c = t >> 10, tid = threadIdx.x;
    __shared__ float agr[1024];
    __shared__ float qrow[128];
    __shared__ int hist[256];
    __shared__ int scan[256];
    __shared__ float red[256];
    __shared__ int chosen_s, gsel_s;
    if (tid < 128) qrow[tid] = tanhpt[(size_t)t * 128 + tid];
    __syncthreads();
    for (int s = tid; s < 1024; s += 256) {
        const float* pn = tanhpn + ((size_t)c * 1024 + s) * 128;
        float acc = 0.0f;
        #pragma unroll 8
        for (int d = 0; d < 128; ++d) acc += qrow[d] * pn[d];
        agr[s] = acc * (1.0f / 128.0f);
    }
    const bf16* lrow = logits + (size_t)t * 1024;
    float v[4];
    #pragma unroll
    for (int j = 0; j < 4; ++j) v[j] = b2f(lrow[4 * tid + j]);
    __syncthreads();
    float mres[2];
    for (int p = 0; p < 2; ++p) {
        unsigned key[4];
        #pragma unroll
        for (int j = 0; j < 4; ++j) key[j] = fkey(p ? -v[j] : v[j]);
        unsigned prefix = 0;
        int gsel = 0;
        for (int pass = 0; pass < 4; ++pass) {
            int shift = 24 - 8 * pass;
            hist[tid] = 0;
            __syncthreads();
            #pragma unroll
            for (int j = 0; j < 4; ++j) {
                bool match = (pass == 0) || ((key[j] >> (shift + 8)) == prefix);
                if (match) atomicAdd(&hist[(key[j] >> shift) & 255], 1);
            }
            __syncthreads();
            if (tid == 0) {
                int need = 64 - gsel;
                int acc = 0, b = 255;
                for (; b >= 0; --b) {
                    int h = hist[b];
                    if (acc + h >= need) break;
                    acc += h;
                }
                chosen_s = b;
                gsel_s = gsel + acc;
            }
            __syncthreads();
            prefix = (prefix << 8) | (unsigned)chosen_s;
            gsel = gsel_s;
        }
        unsigned kstar = prefix;
        int need_eq = 64 - gsel;
        float asum = 0.0f;
        int eqc = 0;
        #pragma unroll
        for (int j = 0; j < 4; ++j) {
            if (key[j] > kstar) asum += agr[4 * tid + j];
            else if (key[j] == kstar) eqc++;
        }
        scan[tid] = eqc;
        __syncthreads();
        for (int o = 1; o < 256; o <<= 1) {
            int val = (tid >= o) ? scan[tid - o] : 0;
            __syncthreads();
            scan[tid] += val;
            __syncthreads();
        }
        int eqr = scan[tid] - eqc;
        #pragma unroll
        for (int j = 0; j < 4; ++j) {
            if (key[j] == kstar) { if (eqr < need_eq) asum += agr[4 * tid + j]; eqr++; }
        }
        red[tid] = asum;
        __syncthreads();
        for (int o = 128; o > 0; o >>= 1) {
            if (tid < o) red[tid] += red[tid + o];
            __syncthreads();
        }
        mres[p] = red[0] * (1.0f / 64.0f);
        __syncthreads();
    }
    if (tid == 0) {
        float r = mres[1] - mres[0] + 0.5f;
        trip[t] = r > 0.0f ? r : 0.0f;
    }
}

__global__ __launch_bounds__(256)
void trip_mean_kernel(const float* __restrict__ trip, float* __restrict__ out)
{
    int tid = threadIdx.x;
    float s = 0.0f;
    for (int i = tid; i < 2048; i += 256) s += trip[i];
    __shared__ float rs[256];
    rs[tid] = s; __syncthreads();
    for (int o = 128; o > 0; o >>= 1) { if (tid < o) rs[tid] += rs[tid + o]; __syncthreads(); }
    if (tid == 0) out[2097152] = rs[0] * (1.0f / 2048.0f);
}

// ============================ launch ============================
extern "C" void kernel_launch(void* const* d_in, const int* in_sizes, int n_in,
                              void* d_out, int out_size, void* d_ws, size_t ws_size,
                              hipStream_t stream)
{
    const float* hidden = (const float*)d_in[0];
    const float* amask  = (const float*)d_in[1];
    const float* ln1g   = (const float*)d_in[2];
    const float* ln1b   = (const float*)d_in[3];
    const float* Wq     = (const float*)d_in[4];
    const float* bq     = (const float*)d_in[5];
    const float* Wk     = (const float*)d_in[6];
    const float* bk     = (const float*)d_in[7];
    const float* Wv     = (const float*)d_in[8];
    const float* bv     = (const float*)d_in[9];
    const float* Wo     = (const float*)d_in[10];
    const float* bo     = (const float*)d_in[11];
    const float* ln2g   = (const float*)d_in[12];
    const float* ln2b   = (const float*)d_in[13];
    const float* W1     = (const float*)d_in[14];
    const float* b1     = (const float*)d_in[15];
    const float* Whash  = (const float*)d_in[16];
    const float* W2     = (const float*)d_in[17];
    const float* b2w    = (const float*)d_in[18];
    float* out = (float*)d_out;
    float* ws  = (float*)d_ws;
    const size_t MB = 1024 * 1024;
    if (ws_size < 20 * MB) return;

    // ---- ws layout (floats), 20 MB ----
    float* xln    = ws;                 // [0,8MB)
    float* qg     = ws + 2097152;       // [8,12MB)
    float* kg     = ws + 3145728;       // [12,16MB)
    float* vg     = ws + 4194304;       // [16,20MB)
    float* attnO  = ws + 2097152;       // [8,16MB) after flash
    float* normed = ws;                 // [0,8MB)
    bf16*  logits = (bf16*)(ws + 4194304); // [16,20MB)
    int*   sids_ws = (int*)ws;          // [0,8KB) after normed dead

    // ---- d_out scratch layout (floats) ----
    float* ctx    = out;
    float* projn  = out;
    float* tanhpt = out + 524288;
    float* tanhpn = out + 786432;
    int*   dints  = (int*)out + 1048576;
    int*   code_n = dints;
    int*   code_t = dints + 65536;
    int*   hist   = dints + 98304;
    int*   score  = dints + 106496;
    int*   shist  = dints + 114688;
    int*   selmeta= dints + 147460;
    int*   sids   = dints + 147464;
    float* trip   = (float*)(dints + 149512);

    // ---- attention (2 head-groups of 8; f32) ----
    ln_kernel<<<2048, 256, 0, stream>>>(hidden, ln1g, ln1b, xln);
    for (int g = 0; g < 2; ++g) {
        const size_t wOff = (size_t)g * 512 * 1024;
        qkv_kernel<<<dim3(8, 16, 3), 256, 0, stream>>>(xln, Wq + wOff, Wk + wOff, Wv + wOff,
                                                       bq + g * 512, bk + g * 512, bv + g * 512,
                                                       qg, kg, vg);
        flash_kernel<<<dim3(32, 8), 256, 0, stream>>>(qg, kg, vg, amask, ctx, g * 8);
    }
    gemm_f32_big<<<dim3(16, 16, 1), 256, 0, stream>>>(ctx, 1024, Wo, 1024, nullptr, bo, hidden,
                                                      attnO, 0, 1024, 0, 2048, 1024, 0, 0, 0);

    // ---- FFN routing (hash projections stay f64-accumulated: sign-critical) ----
    ln_kernel<<<2048, 256, 0, stream>>>(attnO, ln2g, ln2b, normed);
    gemm_nt_t<double><<<dim3(2, 64), 256, 0, stream>>>(W1, 1024, Whash, 1024, nullptr, nullptr, nullptr, projn, 0, 0, 3, 4096, 128, 1024);
    code_n_kernel<<<256, 256, 0, stream>>>(projn, code_n, hist);
    gemm_nt_t<double><<<dim3(2, 32), 256, 0, stream>>>(normed, 1024, Whash, 1024, nullptr, nullptr, nullptr, tanhpt, 0, 128, 0, 2048, 128, 1024);
    code_t_kernel<<<128, 256, 0, stream>>>(tanhpt, code_t);
    hist_kernel<<<128, 256, 0, stream>>>(code_t, hist);
    score_kernel<<<32, 256, 0, stream>>>(hist, code_n, score, shist);
    select_kernel<<<2, 256, 0, stream>>>(shist, selmeta);
    build_sids_kernel<<<2, 256, 0, stream>>>(score, selmeta, sids);
    tanhpn_kernel<<<1024, 256, 0, stream>>>(projn, sids, tanhpn);

    // ---- logits (bf16, ws; f32 acc), both chunks in one launch ----
    gemm_f32_big<<<dim3(16, 8, 2), 256, 0, stream>>>(normed, 1024, W1, 1024, sids, b1, nullptr,
                                                     logits, 1, 1024, 0, 2048, 1024,
                                                     1048576, 1048576, 1024);

    // ---- triplet (reads d_out scratch; must precede final writes) ----
    topk_kernel<<<2048, 256, 0, stream>>>(logits, tanhpt, tanhpn, trip);
    trip_mean_kernel<<<1, 256, 0, stream>>>(trip, out);

    // ---- final FFN output (overwrites d_out matrix) ----
    copy_int_kernel<<<8, 256, 0, stream>>>(sids, sids_ws, 2048);
    out_kernel<<<dim3(16, 8, 2), 256, 0, stream>>>(logits, W2, sids_ws, b2w, attnO, out);
}

// Round 14
// 1486.219 us; speedup vs baseline: 1.0992x; 1.0992x over previous
//
#include <hip/hip_runtime.h>
#include <hip/hip_bf16.h>
#include <math.h>

typedef __hip_bfloat16 bf16;
__device__ __forceinline__ float b2f(bf16 x) { return __bfloat162float(x); }
// order-preserving float->uint key (larger float => larger key)
__device__ __forceinline__ unsigned fkey(float f) {
    unsigned u = __float_as_uint(f);
    return (u & 0x80000000u) ? ~u : (u | 0x80000000u);
}

#define LN_EPS 1e-12f
#define NEG_INF (-3.0e38f)

__global__ __launch_bounds__(256)
void copy_int_kernel(const int* __restrict__ src, int* __restrict__ dst, int n)
{
    int i = blockIdx.x * 256 + threadIdx.x;
    if (i < n) dst[i] = src[i];
}

// ============================ LayerNorm (f32 -> f32, f64 stats) ============================
__global__ __launch_bounds__(256)
void ln_kernel(const float* __restrict__ in, const float* __restrict__ g,
               const float* __restrict__ b, float* __restrict__ out)
{
    const int D = 1024;
    int row = blockIdx.x, tid = threadIdx.x;
    size_t base = (size_t)row * D + tid * 4;
    float x[4];
    #pragma unroll
    for (int i = 0; i < 4; ++i) x[i] = in[base + i];
    double s  = (double)x[0] + x[1] + x[2] + x[3];
    double sq = (double)x[0]*x[0] + (double)x[1]*x[1] + (double)x[2]*x[2] + (double)x[3]*x[3];
    __shared__ double rs[256], rq[256];
    rs[tid] = s; rq[tid] = sq;
    __syncthreads();
    for (int o = 128; o > 0; o >>= 1) {
        if (tid < o) { rs[tid] += rs[tid + o]; rq[tid] += rq[tid + o]; }
        __syncthreads();
    }
    double mean = rs[0] * (1.0 / D);
    double var  = rq[0] * (1.0 / D) - mean * mean;
    double inv  = rsqrt(var + (double)LN_EPS);
    #pragma unroll
    for (int i = 0; i < 4; ++i) {
        int col = tid * 4 + i;
        out[base + i] = (float)(((double)x[i] - mean) * inv * (double)g[col] + (double)b[col]);
    }
}

// ============================ generic NT GEMM (f32 storage, templated accumulator) =========
#define BM 64
#define BN 64
#define BK 16
template<typename ACC>
__global__ __launch_bounds__(256)
void gemm_nt_t(const float* __restrict__ A, int lda,
               const float* __restrict__ B, int ldb,
               const int* __restrict__ gatherB,
               const float* __restrict__ bias,
               const float* __restrict__ residual,
               void* __restrict__ out_, int oBf, int ldc, int mode,
               int M, int N, int Kd)
{
    __shared__ __align__(16) float As[BK][BM + 4];
    __shared__ __align__(16) float Bs[BK][BN + 4];
    int tid = threadIdx.x;
    int bm = blockIdx.y * BM, bn = blockIdx.x * BN;
    int lm  = tid >> 2;
    int lk4 = (tid & 3) * 4;
    int tm = (tid >> 4) * 4, tn = (tid & 15) * 4;
    ACC acc[4][4] = {};
    for (int k0 = 0; k0 < Kd; k0 += BK) {
        {
            const float* p = A + (size_t)(bm + lm) * lda + k0 + lk4;
            #pragma unroll
            for (int i = 0; i < 4; ++i) As[lk4 + i][lm] = p[i];
        }
        {
            int r = bn + lm;
            if (gatherB) r = gatherB[r] & 4095;
            const float* p = B + (size_t)r * ldb + k0 + lk4;
            #pragma unroll
            for (int i = 0; i < 4; ++i) Bs[lk4 + i][lm] = p[i];
        }
        __syncthreads();
        #pragma unroll
        for (int k = 0; k < BK; ++k) {
            float4 av = *(const float4*)&As[k][tm];
            float4 bw = *(const float4*)&Bs[k][tn];
            float avx[4] = {av.x, av.y, av.z, av.w};
            float bwx[4] = {bw.x, bw.y, bw.z, bw.w};
            #pragma unroll
            for (int i = 0; i < 4; ++i)
                #pragma unroll
                for (int j = 0; j < 4; ++j)
                    acc[i][j] += (ACC)avx[i] * (ACC)bwx[j];
        }
        __syncthreads();
    }
    #pragma unroll
    for (int i = 0; i < 4; ++i) {
        int m = bm + tm + i;
        #pragma unroll
        for (int j = 0; j < 4; ++j) {
            int n = bn + tn + j;
            ACC v = acc[i][j];
            if (bias) { int bi2 = gatherB ? (gatherB[n] & 4095) : n; v += (ACC)bias[bi2]; }
            if (residual) v += (ACC)residual[(size_t)m * ldc + n];
            size_t idx;
            if (mode == 0)      idx = (size_t)m * ldc + n;
            else if (mode == 1) idx = (size_t)(n >> 6) * ((size_t)M * 64) + (size_t)m * 64 + (n & 63);
            else                idx = (size_t)(n >> 3) * ((size_t)M * 8) + (size_t)m * 8 + (n & 7);
            if (oBf) ((bf16*)out_)[idx] = __float2bfloat16((float)v);
            else     ((float*)out_)[idx] = (float)v;
        }
    }
}

// ============================ QKV fused (z selects Q/K/V), f32 acc, mode1 out ==============
__global__ __launch_bounds__(256)
void qkv_kernel(const float* __restrict__ A,
                const float* __restrict__ Wq, const float* __restrict__ Wk, const float* __restrict__ Wv,
                const float* __restrict__ bq, const float* __restrict__ bk, const float* __restrict__ bv,
                float* __restrict__ qo, float* __restrict__ ko, float* __restrict__ vo)
{
    const int lda = 1024, ldb = 1024, Kd = 1024, M = 2048;
    const float* B    = (blockIdx.z == 0) ? Wq : (blockIdx.z == 1) ? Wk : Wv;
    const float* bias = (blockIdx.z == 0) ? bq : (blockIdx.z == 1) ? bk : bv;
    float* out        = (blockIdx.z == 0) ? qo : (blockIdx.z == 1) ? ko : vo;
    __shared__ __align__(16) float As[BK][BM + 4];
    __shared__ __align__(16) float Bs[BK][BN + 4];
    int tid = threadIdx.x;
    int bm = blockIdx.y * BM, bn = blockIdx.x * BN;
    int lm  = tid >> 2;
    int lk4 = (tid & 3) * 4;
    int tm = (tid >> 4) * 4, tn = (tid & 15) * 4;
    float acc[4][4] = {};
    for (int k0 = 0; k0 < Kd; k0 += BK) {
        {
            const float* p = A + (size_t)(bm + lm) * lda + k0 + lk4;
            #pragma unroll
            for (int i = 0; i < 4; ++i) As[lk4 + i][lm] = p[i];
        }
        {
            const float* p = B + (size_t)(bn + lm) * ldb + k0 + lk4;
            #pragma unroll
            for (int i = 0; i < 4; ++i) Bs[lk4 + i][lm] = p[i];
        }
        __syncthreads();
        #pragma unroll
        for (int k = 0; k < BK; ++k) {
            float4 av = *(const float4*)&As[k][tm];
            float4 bw = *(const float4*)&Bs[k][tn];
            float avx[4] = {av.x, av.y, av.z, av.w};
            float bwx[4] = {bw.x, bw.y, bw.z, bw.w};
            #pragma unroll
            for (int i = 0; i < 4; ++i)
                #pragma unroll
                for (int j = 0; j < 4; ++j)
                    acc[i][j] += avx[i] * bwx[j];
        }
        __syncthreads();
    }
    #pragma unroll
    for (int i = 0; i < 4; ++i) {
        int m = bm + tm + i;
        #pragma unroll
        for (int j = 0; j < 4; ++j) {
            int n = bn + tn + j;
            float v = acc[i][j] + bias[n];
            size_t idx = (size_t)(n >> 6) * ((size_t)M * 64) + (size_t)m * 64 + (n & 63);
            out[idx] = v;
        }
    }
}

// ============================ logits GEMM (z = chunk), f32 acc, bf16 out ===================
__global__ __launch_bounds__(256)
void logits_kernel(const float* __restrict__ normed, const float* __restrict__ W1,
                   const int* __restrict__ sids, const float* __restrict__ b1,
                   bf16* __restrict__ logits)
{
    const int lda = 1024, ldb = 1024, ldc = 1024, Kd = 1024;
    size_t chOff = (size_t)blockIdx.z * 1048576;
    const float* A = normed + chOff;
    const int* gk = sids + blockIdx.z * 1024;
    bf16* out = logits + chOff;
    __shared__ __align__(16) float As[BK][BM + 4];
    __shared__ __align__(16) float Bs[BK][BN + 4];
    int tid = threadIdx.x;
    int bm = blockIdx.y * BM, bn = blockIdx.x * BN;
    int lm  = tid >> 2;
    int lk4 = (tid & 3) * 4;
    int tm = (tid >> 4) * 4, tn = (tid & 15) * 4;
    float acc[4][4] = {};
    for (int k0 = 0; k0 < Kd; k0 += BK) {
        {
            const float* p = A + (size_t)(bm + lm) * lda + k0 + lk4;
            #pragma unroll
            for (int i = 0; i < 4; ++i) As[lk4 + i][lm] = p[i];
        }
        {
            int r = gk[bn + lm] & 4095;
            const float* p = W1 + (size_t)r * ldb + k0 + lk4;
            #pragma unroll
            for (int i = 0; i < 4; ++i) Bs[lk4 + i][lm] = p[i];
        }
        __syncthreads();
        #pragma unroll
        for (int k = 0; k < BK; ++k) {
            float4 av = *(const float4*)&As[k][tm];
            float4 bw = *(const float4*)&Bs[k][tn];
            float avx[4] = {av.x, av.y, av.z, av.w};
            float bwx[4] = {bw.x, bw.y, bw.z, bw.w};
            #pragma unroll
            for (int i = 0; i < 4; ++i)
                #pragma unroll
                for (int j = 0; j < 4; ++j)
                    acc[i][j] += avx[i] * bwx[j];
        }
        __syncthreads();
    }
    #pragma unroll
    for (int i = 0; i < 4; ++i) {
        int m = bm + tm + i;
        #pragma unroll
        for (int j = 0; j < 4; ++j) {
            int n = bn + tn + j;
            float v = acc[i][j] + b1[gk[n] & 4095];
            out[(size_t)m * ldc + n] = __float2bfloat16(v);
        }
    }
}

// ==== output GEMM (z = chunk): gelu(logits) @ W2[sids] + b2 + attnO -> d_out ====
__global__ __launch_bounds__(256)
void out_kernel(const bf16* __restrict__ logits, const float* __restrict__ W2,
                const int* __restrict__ sids, const float* __restrict__ b2w,
                const float* __restrict__ attnO, float* __restrict__ out)
{
    const int lda = 1024, ldb = 1024, ldc = 1024, Kd = 1024;
    size_t chOff = (size_t)blockIdx.z * 1048576;
    const bf16* A = logits + chOff;
    const int* gk = sids + blockIdx.z * 1024;
    const float* residual = attnO + chOff;
    __shared__ __align__(16) float As[BK][BM + 4];
    __shared__ __align__(16) float Bs[BK][BN + 4];
    int tid = threadIdx.x;
    int bm = blockIdx.y * BM, bn = blockIdx.x * BN;
    int lm  = tid >> 2;
    int lk4 = (tid & 3) * 4;
    int bkr = tid >> 4;
    int bn4 = (tid & 15) * 4;
    int tm = (tid >> 4) * 4, tn = (tid & 15) * 4;
    float acc[4][4] = {};
    for (int k0 = 0; k0 < Kd; k0 += BK) {
        {
            const bf16* p = A + (size_t)(bm + lm) * lda + k0 + lk4;
            #pragma unroll
            for (int i = 0; i < 4; ++i) {
                float x = b2f(p[i]);
                As[lk4 + i][lm] = 0.5f * x * (1.0f + erff(x * 0.70710678118654752f));
            }
        }
        {
            int r = gk[k0 + bkr] & 4095;
            const float* q = W2 + (size_t)r * ldb + bn + bn4;
            #pragma unroll
            for (int i = 0; i < 4; ++i) Bs[bkr][bn4 + i] = q[i];
        }
        __syncthreads();
        #pragma unroll
        for (int k = 0; k < BK; ++k) {
            float4 av = *(const float4*)&As[k][tm];
            float4 bw = *(const float4*)&Bs[k][tn];
            float avx[4] = {av.x, av.y, av.z, av.w};
            float bwx[4] = {bw.x, bw.y, bw.z, bw.w};
            #pragma unroll
            for (int i = 0; i < 4; ++i)
                #pragma unroll
                for (int j = 0; j < 4; ++j)
                    acc[i][j] += avx[i] * bwx[j];
        }
        __syncthreads();
    }
    #pragma unroll
    for (int i = 0; i < 4; ++i) {
        int m = bm + tm + i;
        #pragma unroll
        for (int j = 0; j < 4; ++j) {
            int n = bn + tn + j;
            float v = acc[i][j] + b2w[n] + residual[(size_t)m * ldc + n];
            out[chOff + (size_t)m * ldc + n] = v;
        }
    }
}

// ============================ flash attention v6 ============================
// Q-tile 32, grid (64,8) = 512 blocks (2 blocks/CU). All f32, no max-shift.
// Separate K/V LDS buffers + register prefetch of kt+1's K,V issued right after
// barrier A -> global-load latency hidden by a full iteration. 3 barriers/kt.
// Per-row FP order identical to v4 (round 12) -> bit-identical output.
__global__ __launch_bounds__(256)
void flash_kernel(const float* __restrict__ q, const float* __restrict__ k,
                  const float* __restrict__ v, const float* __restrict__ amask,
                  float* __restrict__ ctx, int hbase)
{
    int qt = blockIdx.x, hl = blockIdx.y, tid = threadIdx.x;
    int ty = tid >> 4, tx = tid & 15;
    int r0 = ty * 2;
    __shared__ __align__(16) float Qs[32][76];
    __shared__ __align__(16) float Ks[64][76];
    __shared__ __align__(16) float Vs[64][76];
    __shared__ __align__(16) float St[32][76];
    __shared__ float lrow[32], msk[64];
    const float* qh = q + (size_t)hl * 131072 + (size_t)qt * 2048;
    #pragma unroll
    for (int rep = 0; rep < 2; ++rep) {
        int lin = rep * 1024 + tid * 4;
        int r = lin >> 6, c = lin & 63;
        *(float4*)&Qs[r][c] = *(const float4*)(qh + lin);
    }
    if (tid < 32) lrow[tid] = 0.0f;
    // prefetch kt = 0
    const float* kh = k + (size_t)hl * 131072;
    const float* vh = v + (size_t)hl * 131072;
    float4 kf[4], vf[4];
    #pragma unroll
    for (int rep = 0; rep < 4; ++rep) {
        int lin = rep * 1024 + tid * 4;
        kf[rep] = *(const float4*)(kh + lin);
        vf[rep] = *(const float4*)(vh + lin);
    }
    float o0[4] = {}, o1[4] = {};
    for (int kt = 0; kt < 32; ++kt) {
        #pragma unroll
        for (int rep = 0; rep < 4; ++rep) {
            int lin = rep * 1024 + tid * 4;
            int r = lin >> 6, c = lin & 63;
            *(float4*)&Ks[r][c] = kf[rep];
            *(float4*)&Vs[r][c] = vf[rep];
        }
        if (tid < 64) msk[tid] = 1000.0f * (1.0f - amask[kt * 64 + tid]);
        __syncthreads();   // barrier A: K,V,msk in LDS
        if (kt < 31) {
            const float* khn = k + (size_t)hl * 131072 + (size_t)(kt + 1) * 4096;
            const float* vhn = v + (size_t)hl * 131072 + (size_t)(kt + 1) * 4096;
            #pragma unroll
            for (int rep = 0; rep < 4; ++rep) {
                int lin = rep * 1024 + tid * 4;
                kf[rep] = *(const float4*)(khn + lin);
                vf[rep] = *(const float4*)(vhn + lin);
            }
        }
        // scores (f32), lane owns cols tx+16j
        float sc0[4] = {}, sc1[4] = {};
        #pragma unroll 4
        for (int d = 0; d < 64; d += 4) {
            float4 q0 = *(const float4*)&Qs[r0][d];
            float4 q1 = *(const float4*)&Qs[r0 + 1][d];
            #pragma unroll
            for (int j = 0; j < 4; ++j) {
                float4 kv = *(const float4*)&Ks[tx + 16 * j][d];
                sc0[j] += q0.x * kv.x + q0.y * kv.y + q0.z * kv.z + q0.w * kv.w;
                sc1[j] += q1.x * kv.x + q1.y * kv.y + q1.z * kv.z + q1.w * kv.w;
            }
        }
        // P = exp(s) without max shift; accumulate l
        float sum0 = 0.0f, sum1 = 0.0f;
        #pragma unroll
        for (int j = 0; j < 4; ++j) {
            float p0 = expf(sc0[j] * 0.125f - msk[tx + 16 * j]);
            float p1 = expf(sc1[j] * 0.125f - msk[tx + 16 * j]);
            St[r0][tx + 16 * j] = p0; St[r0 + 1][tx + 16 * j] = p1;
            sum0 += p0; sum1 += p1;
        }
        #pragma unroll
        for (int off = 1; off < 16; off <<= 1) {
            sum0 += __shfl_xor(sum0, off, 16);
            sum1 += __shfl_xor(sum1, off, 16);
        }
        if (tx == 0) { lrow[r0] += sum0; lrow[r0 + 1] += sum1; }
        __syncthreads();   // barrier B: St ready (scores done with Ks)
        // O += P V
        for (int j2 = 0; j2 < 64; j2 += 4) {
            float4 p0v = *(const float4*)&St[r0][j2];
            float4 p1v = *(const float4*)&St[r0 + 1][j2];
            float p0a[4] = {p0v.x, p0v.y, p0v.z, p0v.w};
            float p1a[4] = {p1v.x, p1v.y, p1v.z, p1v.w};
            #pragma unroll
            for (int e = 0; e < 4; ++e) {
                float4 vv = *(const float4*)&Vs[j2 + e][tx * 4];
                o0[0] += p0a[e] * vv.x; o0[1] += p0a[e] * vv.y; o0[2] += p0a[e] * vv.z; o0[3] += p0a[e] * vv.w;
                o1[0] += p1a[e] * vv.x; o1[1] += p1a[e] * vv.y; o1[2] += p1a[e] * vv.z; o1[3] += p1a[e] * vv.w;
            }
        }
        __syncthreads();   // barrier C: PV done reading Vs/St; Ks reads long done
    }
    float inv0 = 1.0f / lrow[r0], inv1 = 1.0f / lrow[r0 + 1];
    size_t base0 = (size_t)(qt * 32 + r0) * 1024 + (hbase + hl) * 64 + tx * 4;
    size_t base1 = base0 + 1024;
    #pragma unroll
    for (int j = 0; j < 4; ++j) {
        ctx[base0 + j] = o0[j] * inv0;
        ctx[base1 + j] = o1[j] * inv1;
    }
}

// ============================ hashing / routing ============================
__global__ __launch_bounds__(256)
void code_n_kernel(const float* __restrict__ projn, int* __restrict__ code_n,
                   int* __restrict__ zero_base)
{
    int i = blockIdx.x * 256 + threadIdx.x;
    const float* p = projn + (size_t)i * 8;
    int code = 0;
    #pragma unroll
    for (int k = 0; k < 8; ++k) code |= ((int)(p[k] > 0.0f)) << k;
    code_n[i] = code;
    if (i < 49156) zero_base[i] = 0;
}

__global__ __launch_bounds__(256)
void code_t_kernel(float* __restrict__ pt, int* __restrict__ code_t)
{
    int i = blockIdx.x * 256 + threadIdx.x;
    int t = i >> 4, l = i & 15;
    float* p = pt + (size_t)t * 128 + l * 8;
    int code = 0;
    #pragma unroll
    for (int k = 0; k < 8; ++k) {
        float v = p[k];
        code |= ((int)(v > 0.0f)) << k;
        p[k] = tanhf(v);
    }
    code_t[l * 2048 + t] = code;
}

__global__ __launch_bounds__(256)
void hist_kernel(const int* __restrict__ code_t, int* __restrict__ hist)
{
    int i = blockIdx.x * 256 + threadIdx.x;
    int c = i >> 14, l = (i >> 10) & 15, t = i & 1023;
    int code = code_t[l * 2048 + c * 1024 + t] & 255;
    atomicAdd(&hist[(c * 16 + l) * 256 + code], 1);
}

__global__ __launch_bounds__(256)
void score_kernel(const int* __restrict__ hist, const int* __restrict__ code_n,
                  int* __restrict__ score, int* __restrict__ shist)
{
    int i = blockIdx.x * 256 + threadIdx.x;
    int c = i >> 12, n = i & 4095;
    int s = 0;
    #pragma unroll
    for (int l = 0; l < 16; ++l) s += hist[(c * 16 + l) * 256 + (code_n[l * 4096 + n] & 255)];
    if (s < 0) s = 0; if (s > 16384) s = 16384;
    score[c * 4096 + n] = s;
    atomicAdd(&shist[c * 16385 + s], 1);
}

__global__ __launch_bounds__(256)
void select_kernel(const int* __restrict__ shist, int* __restrict__ selmeta)
{
    int c = blockIdx.x, tid = threadIdx.x;
    const int* bins = shist + c * 16385;
    __shared__ int psum[256];
    int s = 0;
    for (int i = 0; i < 64; ++i) s += bins[tid * 64 + i];
    if (tid == 255) s += bins[16384];
    psum[tid] = s;
    __syncthreads();
    if (tid == 0) {
        int cum = 0, sstar = 0, cntge = 0;
        for (int t = 255; t >= 0; --t) {
            if (cum + psum[t] >= 1024) {
                int hi = (t == 255) ? 16384 : t * 64 + 63;
                for (int b = hi; b >= t * 64; --b) {
                    cum += bins[b];
                    if (cum >= 1024) { sstar = b; cntge = cum; break; }
                }
                break;
            }
            cum += psum[t];
        }
        selmeta[c * 2]     = sstar;
        selmeta[c * 2 + 1] = 1024 - (cntge - bins[sstar]);
    }
}

__global__ __launch_bounds__(256)
void build_sids_kernel(const int* __restrict__ score, const int* __restrict__ selmeta,
                       int* __restrict__ sids)
{
    int c = blockIdx.x, tid = threadIdx.x;
    const int* sc2 = score + c * 4096;
    int sstar = selmeta[c * 2], need_eq = selmeta[c * 2 + 1];
    __shared__ int scan[256];
    int base = tid * 16;
    int mysc[16];
    int eqc = 0;
    #pragma unroll
    for (int i = 0; i < 16; ++i) { mysc[i] = sc2[base + i]; eqc += (mysc[i] == sstar); }
    scan[tid] = eqc; __syncthreads();
    for (int o = 1; o < 256; o <<= 1) {
        int v = (tid >= o) ? scan[tid - o] : 0;
        __syncthreads();
        scan[tid] += v;
        __syncthreads();
    }
    int eqr = scan[tid] - eqc;
    __syncthreads();
    int selc = 0; unsigned flags = 0;
    #pragma unroll
    for (int i = 0; i < 16; ++i) {
        bool sel = false;
        if (mysc[i] > sstar) sel = true;
        else if (mysc[i] == sstar) { sel = (eqr < need_eq); eqr++; }
        if (sel) { flags |= (1u << i); selc++; }
    }
    scan[tid] = selc; __syncthreads();
    for (int o = 1; o < 256; o <<= 1) {
        int v = (tid >= o) ? scan[tid - o] : 0;
        __syncthreads();
        scan[tid] += v;
        __syncthreads();
    }
    int pos = scan[tid] - selc;
    #pragma unroll
    for (int i = 0; i < 16; ++i)
        if (flags & (1u << i)) { if (pos < 1024) sids[c * 1024 + pos] = base + i; pos++; }
}

__global__ __launch_bounds__(256)
void tanhpn_kernel(const float* __restrict__ projn, const int* __restrict__ sids,
                   float* __restrict__ tanhpn)
{
    int i = blockIdx.x * 256 + threadIdx.x;
    int c = i >> 17;
    int r = i & 131071;
    int s = r >> 7, j = r & 127;
    int l = j >> 3, k = j & 7;
    int n = sids[c * 1024 + s] & 4095;
    tanhpn[(size_t)c * 131072 + (size_t)s * 128 + j] = tanhf(projn[(size_t)l * 32768 + (size_t)n * 8 + k]);
}

// ============================ topk: radix-select per row ============================
__global__ __launch_bounds__(256)
void topk_kernel(const bf16* __restrict__ logits, const float* __restrict__ tanhpt,
                 const float* __restrict__ tanhpn, float* __restrict__ trip)
{
    int t = blockIdx.x;
    int c = t >> 10, tid = threadIdx.x;
    __shared__ float agr[1024];
    __shared__ float qrow[128];
    __shared__ int hist[256];
    __shared__ int scan[256];
    __shared__ float red[256];
    __shared__ int chosen_s, gsel_s;
    if (tid < 128) qrow[tid] = tanhpt[(size_t)t * 128 + tid];
    __syncthreads();
    for (int s = tid; s < 1024; s += 256) {
        const float* pn = tanhpn + ((size_t)c * 1024 + s) * 128;
        float acc = 0.0f;
        #pragma unroll 8
        for (int d = 0; d < 128; ++d) acc += qrow[d] * pn[d];
        agr[s] = acc * (1.0f / 128.0f);
    }
    const bf16* lrow = logits + (size_t)t * 1024;
    float v[4];
    #pragma unroll
    for (int j = 0; j < 4; ++j) v[j] = b2f(lrow[4 * tid + j]);
    __syncthreads();
    float mres[2];
    for (int p = 0; p < 2; ++p) {
        unsigned key[4];
        #pragma unroll
        for (int j = 0; j < 4; ++j) key[j] = fkey(p ? -v[j] : v[j]);
        unsigned prefix = 0;
        int gsel = 0;
        for (int pass = 0; pass < 4; ++pass) {
            int shift = 24 - 8 * pass;
            hist[tid] = 0;
            __syncthreads();
            #pragma unroll
            for (int j = 0; j < 4; ++j) {
                bool match = (pass == 0) || ((key[j] >> (shift + 8)) == prefix);
                if (match) atomicAdd(&hist[(key[j] >> shift) & 255], 1);
            }
            __syncthreads();
            if (tid == 0) {
                int need = 64 - gsel;
                int acc = 0, b = 255;
                for (; b >= 0; --b) {
                    int h = hist[b];
                    if (acc + h >= need) break;
                    acc += h;
                }
                chosen_s = b;
                gsel_s = gsel + acc;
            }
            __syncthreads();
            prefix = (prefix << 8) | (unsigned)chosen_s;
            gsel = gsel_s;
        }
        unsigned kstar = prefix;
        int need_eq = 64 - gsel;
        float asum = 0.0f;
        int eqc = 0;
        #pragma unroll
        for (int j = 0; j < 4; ++j) {
            if (key[j] > kstar) asum += agr[4 * tid + j];
            else if (key[j] == kstar) eqc++;
        }
        scan[tid] = eqc;
        __syncthreads();
        for (int o = 1; o < 256; o <<= 1) {
            int val = (tid >= o) ? scan[tid - o] : 0;
            __syncthreads();
            scan[tid] += val;
            __syncthreads();
        }
        int eqr = scan[tid] - eqc;
        #pragma unroll
        for (int j = 0; j < 4; ++j) {
            if (key[j] == kstar) { if (eqr < need_eq) asum += agr[4 * tid + j]; eqr++; }
        }
        red[tid] = asum;
        __syncthreads();
        for (int o = 128; o > 0; o >>= 1) {
            if (tid < o) red[tid] += red[tid + o];
            __syncthreads();
        }
        mres[p] = red[0] * (1.0f / 64.0f);
        __syncthreads();
    }
    if (tid == 0) {
        float r = mres[1] - mres[0] + 0.5f;
        trip[t] = r > 0.0f ? r : 0.0f;
    }
}

__global__ __launch_bounds__(256)
void trip_mean_kernel(const float* __restrict__ trip, float* __restrict__ out)
{
    int tid = threadIdx.x;
    float s = 0.0f;
    for (int i = tid; i < 2048; i += 256) s += trip[i];
    __shared__ float rs[256];
    rs[tid] = s; __syncthreads();
    for (int o = 128; o > 0; o >>= 1) { if (tid < o) rs[tid] += rs[tid + o]; __syncthreads(); }
    if (tid == 0) out[2097152] = rs[0] * (1.0f / 2048.0f);
}

// ============================ launch ============================
extern "C" void kernel_launch(void* const* d_in, const int* in_sizes, int n_in,
                              void* d_out, int out_size, void* d_ws, size_t ws_size,
                              hipStream_t stream)
{
    const float* hidden = (const float*)d_in[0];
    const float* amask  = (const float*)d_in[1];
    const float* ln1g   = (const float*)d_in[2];
    const float* ln1b   = (const float*)d_in[3];
    const float* Wq     = (const float*)d_in[4];
    const float* bq     = (const float*)d_in[5];
    const float* Wk     = (const float*)d_in[6];
    const float* bk     = (const float*)d_in[7];
    const float* Wv     = (const float*)d_in[8];
    const float* bv     = (const float*)d_in[9];
    const float* Wo     = (const float*)d_in[10];
    const float* bo     = (const float*)d_in[11];
    const float* ln2g   = (const float*)d_in[12];
    const float* ln2b   = (const float*)d_in[13];
    const float* W1     = (const float*)d_in[14];
    const float* b1     = (const float*)d_in[15];
    const float* Whash  = (const float*)d_in[16];
    const float* W2     = (const float*)d_in[17];
    const float* b2w    = (const float*)d_in[18];
    float* out = (float*)d_out;
    float* ws  = (float*)d_ws;
    const size_t MB = 1024 * 1024;
    if (ws_size < 20 * MB) return;

    // ---- ws layout (floats), 20 MB ----
    float* xln    = ws;                 // [0,8MB)
    float* qg     = ws + 2097152;       // [8,12MB)
    float* kg     = ws + 3145728;       // [12,16MB)
    float* vg     = ws + 4194304;       // [16,20MB)
    float* attnO  = ws + 2097152;       // [8,16MB) after flash
    float* normed = ws;                 // [0,8MB)
    bf16*  logits = (bf16*)(ws + 4194304); // [16,20MB)
    int*   sids_ws = (int*)ws;          // [0,8KB) after normed dead

    // ---- d_out scratch layout (floats) ----
    float* ctx    = out;
    float* projn  = out;
    float* tanhpt = out + 524288;
    float* tanhpn = out + 786432;
    int*   dints  = (int*)out + 1048576;
    int*   code_n = dints;
    int*   code_t = dints + 65536;
    int*   hist   = dints + 98304;
    int*   score  = dints + 106496;
    int*   shist  = dints + 114688;
    int*   selmeta= dints + 147460;
    int*   sids   = dints + 147464;
    float* trip   = (float*)(dints + 149512);

    // ---- attention (2 head-groups of 8; f32) ----
    ln_kernel<<<2048, 256, 0, stream>>>(hidden, ln1g, ln1b, xln);
    for (int g = 0; g < 2; ++g) {
        const size_t wOff = (size_t)g * 512 * 1024;
        qkv_kernel<<<dim3(8, 32, 3), 256, 0, stream>>>(xln, Wq + wOff, Wk + wOff, Wv + wOff,
                                                       bq + g * 512, bk + g * 512, bv + g * 512,
                                                       qg, kg, vg);
        flash_kernel<<<dim3(64, 8), 256, 0, stream>>>(qg, kg, vg, amask, ctx, g * 8);
    }
    gemm_nt_t<float><<<dim3(16, 32), 256, 0, stream>>>(ctx, 1024, Wo, 1024, nullptr, bo, hidden, attnO, 0, 1024, 0, 2048, 1024, 1024);

    // ---- FFN routing (hash projections stay f64-accumulated: sign-critical) ----
    ln_kernel<<<2048, 256, 0, stream>>>(attnO, ln2g, ln2b, normed);
    gemm_nt_t<double><<<dim3(2, 64), 256, 0, stream>>>(W1, 1024, Whash, 1024, nullptr, nullptr, nullptr, projn, 0, 0, 3, 4096, 128, 1024);
    code_n_kernel<<<256, 256, 0, stream>>>(projn, code_n, hist);
    gemm_nt_t<double><<<dim3(2, 32), 256, 0, stream>>>(normed, 1024, Whash, 1024, nullptr, nullptr, nullptr, tanhpt, 0, 128, 0, 2048, 128, 1024);
    code_t_kernel<<<128, 256, 0, stream>>>(tanhpt, code_t);
    hist_kernel<<<128, 256, 0, stream>>>(code_t, hist);
    score_kernel<<<32, 256, 0, stream>>>(hist, code_n, score, shist);
    select_kernel<<<2, 256, 0, stream>>>(shist, selmeta);
    build_sids_kernel<<<2, 256, 0, stream>>>(score, selmeta, sids);
    tanhpn_kernel<<<1024, 256, 0, stream>>>(projn, sids, tanhpn);

    // ---- logits (bf16, ws; f32 acc), both chunks in one launch ----
    logits_kernel<<<dim3(16, 16, 2), 256, 0, stream>>>(normed, W1, sids, b1, logits);

    // ---- triplet (reads d_out scratch; must precede final writes) ----
    topk_kernel<<<2048, 256, 0, stream>>>(logits, tanhpt, tanhpn, trip);
    trip_mean_kernel<<<1, 256, 0, stream>>>(trip, out);

    // ---- final FFN output (overwrites d_out matrix) ----
    copy_int_kernel<<<8, 256, 0, stream>>>(sids, sids_ws, 2048);
    out_kernel<<<dim3(16, 16, 2), 256, 0, stream>>>(logits, W2, sids_ws, b2w, attnO, out);
}